// Round 5
// baseline (34447.870 us; speedup 1.0000x reference)
//
#include <hip/hip_runtime.h>
#include <math.h>

#define NINP 64
#define NH 512
#define G4 2048   // 4*NH
#define T 64
#define BATCH 2048
#define LDIN 4097 // T*NINP+1
#define XCOLS 4096

typedef __bf16 bf16x8 __attribute__((ext_vector_type(8)));
typedef float f32x4 __attribute__((ext_vector_type(4)));
typedef unsigned short ushort8 __attribute__((ext_vector_type(8)));
typedef unsigned short ushort4v __attribute__((ext_vector_type(4)));

__device__ __forceinline__ float sigmf(float x) { return 1.0f / (1.0f + expf(-x)); }

__device__ __forceinline__ unsigned int bfhi_bits(float f) {
    unsigned int u = __float_as_uint(f);
    return (u + 0x7fffu + ((u >> 16) & 1u)) >> 16;
}
__device__ __forceinline__ float bf_to_f(unsigned int bits) {
    return __uint_as_float(bits << 16);
}

// ---------------------------------------------------------------------------
// Fused gates-GEMM (split-bf16 MFMA) + LSTM cell epilogue.
// 512 threads / 8 waves (4m x 2n), block tile 128(b) x 64(n'), wave 32x32.
// BK=32. LDS: 64B rows, XOR swizzle slot^=(row>>1)&3  -> conflict-free.
// Double-buffered K-pipeline, register prefetch, 1 barrier per K-step.
// Gate columns PERMUTED: n' = j*4 + g.
// XCD-pinned mapping (bid&7) keeps each XCD's W slice L2-resident.
// Optional prologue: out-projection of previous step's h (+ pia scaling).
// ---------------------------------------------------------------------------
// per-buffer ushort offsets inside smem
#define OFF_AHI 0
#define OFF_ALO 4096
#define OFF_WHI 8192
#define OFF_WLO 10240
#define BUFSZ   12288

__global__ __launch_bounds__(512, 4) void lstm_step_k(
    const ushort* __restrict__ A0hi, const ushort* __restrict__ A0lo, int lda0,
    const ushort* __restrict__ W0hi, const ushort* __restrict__ W0lo, int K0,
    const ushort* __restrict__ A1hi, const ushort* __restrict__ A1lo, int lda1,
    const ushort* __restrict__ W1hi, const ushort* __restrict__ W1lo, int K1,
    const ushort* __restrict__ A2hi, const ushort* __restrict__ A2lo, int lda2,
    const ushort* __restrict__ W2hi, const ushort* __restrict__ W2lo, int K2,
    const float* __restrict__ biasperm,
    const float* __restrict__ pv, const float* __restrict__ pcperm,
    float* __restrict__ c,
    ushort* __restrict__ hhi, ushort* __restrict__ hlo,
    const ushort* __restrict__ ophi, const ushort* __restrict__ oplo,
    const float* __restrict__ Wl, const float* __restrict__ blv,
    const float* __restrict__ scaleBase,
    float* __restrict__ piadst,
    float* __restrict__ odst, int ostride)
{
    __shared__ __align__(16) ushort smem[2 * BUFSZ];   // 49152 B
    float* Gs = (float*)smem;                          // [128][68] aliased

    const int tid = threadIdx.x;
    const int lane = tid & 63;
    const int wid = tid >> 6;
    const int bid = blockIdx.x;

    // XCD-pinned tile mapping
    const int xcd = bid & 7;
    const int idx8 = bid >> 3;
    const int nblk = xcd * 4 + (idx8 & 3);
    const int mblk = idx8 >> 2;
    const int m0 = mblk * 128;
    const int n0 = nblk * 64;

    // ---- prologue: out-projection of previous h ----
    if (ophi != nullptr) {
        int row = bid * 8 + wid;
        if (row < BATCH) {
            ushort8 hh8 = *(const ushort8*)&ophi[(size_t)row * NH + lane * 8];
            ushort8 hl8 = *(const ushort8*)&oplo[(size_t)row * NH + lane * 8];
            const float4* wv = (const float4*)(Wl + lane * 8);
            float4 w0 = wv[0], w1 = wv[1];
            float wreg[8] = {w0.x, w0.y, w0.z, w0.w, w1.x, w1.y, w1.z, w1.w};
            float s = 0.f;
            #pragma unroll
            for (int e = 0; e < 8; ++e) {
                float h = bf_to_f(hh8[e]) + bf_to_f(hl8[e]);
                s = fmaf(h, wreg[e], s);
            }
            #pragma unroll
            for (int off = 32; off > 0; off >>= 1) s += __shfl_down(s, off);
            if (lane == 0) {
                float proj = s + blv[0];
                if (odst) odst[(size_t)row * ostride] = proj;
                if (piadst) piadst[row] = fabsf(proj) * scaleBase[(size_t)row * LDIN + (LDIN - 1)];
            }
        }
    }

    // wave geometry: 4m x 2n, wave tile 32x32
    const int wm = wid >> 1;        // 0..3
    const int wn = wid & 1;         // 0..1
    const int fr = lane & 15;
    const int fg = lane >> 4;
    const int rdsw = (fr >> 1) & 3;            // read swizzle (per-lane const)

    // staging geometry: A: 128 rows x 4 slots (512 thr); W: 64 x 4 x {hi,lo}
    const int arow = tid >> 2;                 // 0..127
    const int aslot = tid & 3;
    const int swa = (aslot ^ ((arow >> 1) & 3)) << 3;
    const int wrow = (tid & 255) >> 2;         // 0..63
    const int sww = (aslot ^ ((wrow >> 1) & 3)) << 3;
    const int wbase = OFF_WHI + ((tid >> 8) << 11);   // hi or lo plane

    const int nt0 = K0 >> 5;
    const int nt1 = K1 >> 5;
    const int nt2 = K2 >> 5;
    const int NT = nt0 + nt1 + nt2;

    ushort8 ra, rl, rw;

    auto issue = [&](int t) {
        const ushort *Ahi, *Alo, *Wp;
        int lda_, K_, kt;
        if (t < nt0)            { Ahi = A0hi; Alo = A0lo; lda_ = lda0; K_ = K0; kt = t * 32;
                                  Wp = (tid < 256) ? W0hi : W0lo; }
        else if (t < nt0 + nt1) { Ahi = A1hi; Alo = A1lo; lda_ = lda1; K_ = K1; kt = (t - nt0) * 32;
                                  Wp = (tid < 256) ? W1hi : W1lo; }
        else                    { Ahi = A2hi; Alo = A2lo; lda_ = lda2; K_ = K2; kt = (t - nt0 - nt1) * 32;
                                  Wp = (tid < 256) ? W2hi : W2lo; }
        ra = *(const ushort8*)&Ahi[(size_t)(m0 + arow) * lda_ + kt + aslot * 8];
        rl = *(const ushort8*)&Alo[(size_t)(m0 + arow) * lda_ + kt + aslot * 8];
        rw = *(const ushort8*)&Wp[(size_t)(n0 + wrow) * K_ + kt + aslot * 8];
    };

    auto dswr = [&](int buf) {
        ushort* bp = smem + buf * BUFSZ;
        *(ushort8*)&bp[OFF_AHI + arow * 32 + swa] = ra;
        *(ushort8*)&bp[OFF_ALO + arow * 32 + swa] = rl;
        *(ushort8*)&bp[wbase + wrow * 32 + sww] = rw;
    };

    f32x4 acc[2][2] = {};
    int cur = 0;

    issue(0);
    dswr(0);

    for (int t = 0; t < NT; ++t) {
        if (t + 1 < NT) issue(t + 1);
        __syncthreads();

        const ushort* bp = smem + cur * BUFSZ;
        bf16x8 ah[2], al[2], wh[2], wl[2];
        #pragma unroll
        for (int im = 0; im < 2; ++im) {
            int off = (wm * 32 + im * 16 + fr) * 32 + ((fg ^ rdsw) << 3);
            ah[im] = *(const bf16x8*)&bp[OFF_AHI + off];
            al[im] = *(const bf16x8*)&bp[OFF_ALO + off];
        }
        #pragma unroll
        for (int in = 0; in < 2; ++in) {
            int off = (wn * 32 + in * 16 + fr) * 32 + ((fg ^ rdsw) << 3);
            wh[in] = *(const bf16x8*)&bp[OFF_WHI + off];
            wl[in] = *(const bf16x8*)&bp[OFF_WLO + off];
        }
        #pragma unroll
        for (int im = 0; im < 2; ++im)
            #pragma unroll
            for (int in = 0; in < 2; ++in)
                acc[im][in] = __builtin_amdgcn_mfma_f32_16x16x32_bf16(ah[im], wh[in], acc[im][in], 0, 0, 0);
        #pragma unroll
        for (int im = 0; im < 2; ++im)
            #pragma unroll
            for (int in = 0; in < 2; ++in)
                acc[im][in] = __builtin_amdgcn_mfma_f32_16x16x32_bf16(ah[im], wl[in], acc[im][in], 0, 0, 0);
        #pragma unroll
        for (int im = 0; im < 2; ++im)
            #pragma unroll
            for (int in = 0; in < 2; ++in)
                acc[im][in] = __builtin_amdgcn_mfma_f32_16x16x32_bf16(al[im], wh[in], acc[im][in], 0, 0, 0);

        if (t + 1 < NT) dswr(cur ^ 1);
        cur ^= 1;
    }

    // ---- epilogue stage 1: bias + pia, fragments -> LDS f32 [128][68] ----
    __syncthreads();
    #pragma unroll
    for (int im = 0; im < 2; ++im) {
        int rowl = wm * 32 + im * 16 + fg * 4;
        #pragma unroll
        for (int in = 0; in < 2; ++in) {
            int npl = wn * 32 + in * 16 + fr;
            int np = n0 + npl;
            float bias = biasperm[np];
            float pcv = (pcperm != nullptr) ? pcperm[np] : 0.0f;
            #pragma unroll
            for (int r = 0; r < 4; ++r) {
                float g = acc[im][in][r] + bias;
                if (pv != nullptr) g += pv[m0 + rowl + r] * pcv;
                Gs[(rowl + r) * 68 + npl] = g;
            }
        }
    }
    __syncthreads();

    // ---- epilogue stage 2: per-cell update, coalesced I/O ----
    {
        int brow = tid >> 2;            // 0..127
        int jgrp = tid & 3;             // 4 j's each
        size_t idx = (size_t)(m0 + brow) * NH + (n0 >> 2) + jgrp * 4;
        float4 cold = *(const float4*)&c[idx];
        float co[4] = {cold.x, cold.y, cold.z, cold.w};
        float cn[4], hn[4];
        #pragma unroll
        for (int jj = 0; jj < 4; ++jj) {
            float4 gv = *(const float4*)&Gs[brow * 68 + jgrp * 16 + jj * 4];
            float cnv = sigmf(gv.y) * co[jj] + sigmf(gv.x) * tanhf(gv.z);
            cn[jj] = cnv;
            hn[jj] = sigmf(gv.w) * tanhf(cnv);
        }
        float4 cs = {cn[0], cn[1], cn[2], cn[3]};
        *(float4*)&c[idx] = cs;
        ushort4v hh, hl;
        #pragma unroll
        for (int jj = 0; jj < 4; ++jj) {
            unsigned int hb = bfhi_bits(hn[jj]);
            hh[jj] = (unsigned short)hb;
            hl[jj] = (unsigned short)bfhi_bits(hn[jj] - bf_to_f(hb));
        }
        *(ushort4v*)&hhi[idx] = hh;
        *(ushort4v*)&hlo[idx] = hl;
    }
}

// Standalone out-projection from hi/lo split h (tail), with optional pia.
__global__ __launch_bounds__(256) void out_proj_hl(const ushort* __restrict__ hhi,
                                                   const ushort* __restrict__ hlo,
                                                   const float* __restrict__ Wl,
                                                   const float* __restrict__ blv,
                                                   const float* __restrict__ scaleBase,
                                                   float* __restrict__ piadst,
                                                   float* __restrict__ odst, int ostride)
{
    int wave = threadIdx.x >> 6;
    int lane = threadIdx.x & 63;
    int row = blockIdx.x * 4 + wave;
    ushort8 hh8 = *(const ushort8*)&hhi[(size_t)row * NH + lane * 8];
    ushort8 hl8 = *(const ushort8*)&hlo[(size_t)row * NH + lane * 8];
    const float4* wv = (const float4*)(Wl + lane * 8);
    float4 w0 = wv[0], w1 = wv[1];
    float wreg[8] = {w0.x, w0.y, w0.z, w0.w, w1.x, w1.y, w1.z, w1.w};
    float s = 0.f;
    #pragma unroll
    for (int e = 0; e < 8; ++e) {
        float h = bf_to_f(hh8[e]) + bf_to_f(hl8[e]);
        s = fmaf(h, wreg[e], s);
    }
    #pragma unroll
    for (int off = 32; off > 0; off >>= 1) s += __shfl_down(s, off);
    if (lane == 0) {
        float proj = s + blv[0];
        if (odst) odst[(size_t)row * ostride] = proj;
        if (piadst) piadst[row] = fabsf(proj) * scaleBase[(size_t)row * LDIN + (LDIN - 1)];
    }
}

// Split W[4NH][ldw] (cols 0..K-1) into permuted bf16 hi/lo, n' = j*4+g.
__global__ __launch_bounds__(256) void split_perm_w_k(const float* __restrict__ W,
                                                      ushort* __restrict__ whi,
                                                      ushort* __restrict__ wlo,
                                                      int ldw, int kshift)
{
    int idx = blockIdx.x * 256 + threadIdx.x;
    int K = 1 << kshift;
    int np = idx >> kshift;
    int k = idx & (K - 1);
    int orig = ((np & 3) << 9) | (np >> 2);
    float v = W[(size_t)orig * ldw + k];
    unsigned int hb = bfhi_bits(v);
    whi[idx] = (unsigned short)hb;
    wlo[idx] = (unsigned short)bfhi_bits(v - bf_to_f(hb));
}

// Split input x (cols 0..4095 of each row) into bf16 hi/lo, layout [b][4096].
__global__ __launch_bounds__(256) void split_x_k(const float* __restrict__ input,
                                                 ushort* __restrict__ xhi,
                                                 ushort* __restrict__ xlo)
{
    int idx = blockIdx.x * 256 + threadIdx.x;   // over BATCH*XCOLS
    int b = idx >> 12;
    int col = idx & (XCOLS - 1);
    float v = input[(size_t)b * LDIN + col];
    unsigned int hb = bfhi_bits(v);
    xhi[idx] = (unsigned short)hb;
    xlo[idx] = (unsigned short)bfhi_bits(v - bf_to_f(hb));
}

__global__ __launch_bounds__(256) void bias_prep_k(const float* __restrict__ bih,
                                                   const float* __restrict__ bhh,
                                                   float* __restrict__ bperm)
{
    int np = blockIdx.x * 256 + threadIdx.x;
    int orig = ((np & 3) << 9) | (np >> 2);
    bperm[np] = bih[orig] + bhh[orig];
}

__global__ __launch_bounds__(256) void pc_prep_k(const float* __restrict__ Wih1,
                                                 float* __restrict__ pc)
{
    int np = blockIdx.x * 256 + threadIdx.x;
    int orig = ((np & 3) << 9) | (np >> 2);
    pc[np] = Wih1[(size_t)orig * (NINP + 1) + NINP];
}

extern "C" void kernel_launch(void* const* d_in, const int* in_sizes, int n_in,
                              void* d_out, int out_size, void* d_ws, size_t ws_size,
                              hipStream_t stream)
{
    const float* input = (const float*)d_in[0];
    const float* Wih_p = (const float*)d_in[1];
    const float* Whh_p = (const float*)d_in[2];
    const float* bih_p = (const float*)d_in[3];
    const float* bhh_p = (const float*)d_in[4];
    const float* Wih1  = (const float*)d_in[5];
    const float* Whh1  = (const float*)d_in[6];
    const float* bih1  = (const float*)d_in[7];
    const float* bhh1  = (const float*)d_in[8];
    const float* Wih2  = (const float*)d_in[9];
    const float* Whh2  = (const float*)d_in[10];
    const float* bih2  = (const float*)d_in[11];
    const float* bhh2  = (const float*)d_in[12];
    const float* Wl    = (const float*)d_in[13];
    const float* bl    = (const float*)d_in[14];
    float* out = (float*)d_out;

    const size_t HC = (size_t)BATCH * NH;       // 1M elems
    char* p = (char*)d_ws;
    auto alloc = [&](size_t bytes) { char* r = p; p += (bytes + 255) & ~(size_t)255; return r; };

    // --- zeroed region first ---
    float* c_p = (float*)alloc(HC * 4);
    float* c1  = (float*)alloc(HC * 4);
    float* c2  = (float*)alloc(HC * 4);
    ushort* hps_hi[2]; ushort* hps_lo[2];
    ushort* h1s_hi[2]; ushort* h1s_lo[2];
    ushort* h2s_hi[2]; ushort* h2s_lo[2];
    for (int i = 0; i < 2; ++i) { hps_hi[i] = (ushort*)alloc(HC * 2); hps_lo[i] = (ushort*)alloc(HC * 2); }
    for (int i = 0; i < 2; ++i) { h1s_hi[i] = (ushort*)alloc(HC * 2); h1s_lo[i] = (ushort*)alloc(HC * 2); }
    for (int i = 0; i < 2; ++i) { h2s_hi[i] = (ushort*)alloc(HC * 2); h2s_lo[i] = (ushort*)alloc(HC * 2); }
    size_t zbytes = (size_t)(p - (char*)d_ws);

    // --- non-zeroed ---
    float* pias   = (float*)alloc((size_t)T * BATCH * 4);
    ushort* WhhP_hi = (ushort*)alloc((size_t)G4 * NH * 2);
    ushort* WhhP_lo = (ushort*)alloc((size_t)G4 * NH * 2);
    ushort* WihP_hi = (ushort*)alloc((size_t)G4 * NINP * 2);
    ushort* WihP_lo = (ushort*)alloc((size_t)G4 * NINP * 2);
    ushort* Whh1_hi = (ushort*)alloc((size_t)G4 * NH * 2);
    ushort* Whh1_lo = (ushort*)alloc((size_t)G4 * NH * 2);
    ushort* Wih1x_hi = (ushort*)alloc((size_t)G4 * NINP * 2);
    ushort* Wih1x_lo = (ushort*)alloc((size_t)G4 * NINP * 2);
    ushort* Wih2_hi = (ushort*)alloc((size_t)G4 * NH * 2);
    ushort* Wih2_lo = (ushort*)alloc((size_t)G4 * NH * 2);
    ushort* Whh2_hi = (ushort*)alloc((size_t)G4 * NH * 2);
    ushort* Whh2_lo = (ushort*)alloc((size_t)G4 * NH * 2);
    ushort* xhi = (ushort*)alloc((size_t)BATCH * XCOLS * 2);
    ushort* xlo = (ushort*)alloc((size_t)BATCH * XCOLS * 2);
    float* biasP = (float*)alloc(G4 * 4);
    float* bias1 = (float*)alloc(G4 * 4);
    float* bias2 = (float*)alloc(G4 * 4);
    float* pc1   = (float*)alloc(G4 * 4);

    hipMemsetAsync(d_ws, 0, zbytes, stream);

    // prep
    split_perm_w_k<<<(G4 * NH) / 256, 256, 0, stream>>>(Whh_p, WhhP_hi, WhhP_lo, NH, 9);
    split_perm_w_k<<<(G4 * NINP) / 256, 256, 0, stream>>>(Wih_p, WihP_hi, WihP_lo, NINP, 6);
    split_perm_w_k<<<(G4 * NH) / 256, 256, 0, stream>>>(Whh1, Whh1_hi, Whh1_lo, NH, 9);
    split_perm_w_k<<<(G4 * NINP) / 256, 256, 0, stream>>>(Wih1, Wih1x_hi, Wih1x_lo, NINP + 1, 6);
    split_perm_w_k<<<(G4 * NH) / 256, 256, 0, stream>>>(Wih2, Wih2_hi, Wih2_lo, NH, 9);
    split_perm_w_k<<<(G4 * NH) / 256, 256, 0, stream>>>(Whh2, Whh2_hi, Whh2_lo, NH, 9);
    split_x_k<<<(BATCH * XCOLS) / 256, 256, 0, stream>>>(input, xhi, xlo);
    bias_prep_k<<<G4 / 256, 256, 0, stream>>>(bih_p, bhh_p, biasP);
    bias_prep_k<<<G4 / 256, 256, 0, stream>>>(bih1, bhh1, bias1);
    bias_prep_k<<<G4 / 256, 256, 0, stream>>>(bih2, bhh2, bias2);
    pc_prep_k<<<G4 / 256, 256, 0, stream>>>(Wih1, pc1);

    dim3 sgrid(512);
    dim3 sblk(512);
    dim3 ogrid(BATCH / 4);

    // Phase 1
    for (int t = 0; t < T; ++t) {
        int rb = t & 1, wb = (t + 1) & 1;
        lstm_step_k<<<sgrid, sblk, 0, stream>>>(
            xhi + (size_t)t * NINP, xlo + (size_t)t * NINP, XCOLS,
            WihP_hi, WihP_lo, NINP,
            hps_hi[rb], hps_lo[rb], NH, WhhP_hi, WhhP_lo, NH,
            nullptr, nullptr, 0, nullptr, nullptr, 0,
            biasP, nullptr, nullptr,
            c_p, hps_hi[wb], hps_lo[wb],
            (t > 0) ? hps_hi[rb] : nullptr, hps_lo[rb], Wl, bl,
            input, (t > 0) ? pias + (size_t)(t - 1) * BATCH : nullptr,
            nullptr, 0);
    }
    out_proj_hl<<<ogrid, 256, 0, stream>>>(hps_hi[T & 1], hps_lo[T & 1], Wl, bl,
                                           input, pias + (size_t)(T - 1) * BATCH,
                                           out + T, T + 1);

    // Phase 2
    for (int t = 0; t < T; ++t) {
        int rb = t & 1, wb = (t + 1) & 1;
        lstm_step_k<<<sgrid, sblk, 0, stream>>>(
            xhi + (size_t)t * NINP, xlo + (size_t)t * NINP, XCOLS,
            Wih1x_hi, Wih1x_lo, NINP,
            h1s_hi[rb], h1s_lo[rb], NH, Whh1_hi, Whh1_lo, NH,
            nullptr, nullptr, 0, nullptr, nullptr, 0,
            bias1, pias + (size_t)t * BATCH, pc1,
            c1, h1s_hi[wb], h1s_lo[wb],
            (t > 0) ? h2s_hi[rb] : nullptr, h2s_lo[rb], Wl, bl,
            input, nullptr,
            (t > 0) ? out + (t - 1) : nullptr, T + 1);
        lstm_step_k<<<sgrid, sblk, 0, stream>>>(
            h1s_hi[wb], h1s_lo[wb], NH, Wih2_hi, Wih2_lo, NH,
            h2s_hi[rb], h2s_lo[rb], NH, Whh2_hi, Whh2_lo, NH,
            nullptr, nullptr, 0, nullptr, nullptr, 0,
            bias2, nullptr, nullptr,
            c2, h2s_hi[wb], h2s_lo[wb],
            nullptr, nullptr, nullptr, nullptr,
            nullptr, nullptr, nullptr, 0);
    }
    out_proj_hl<<<ogrid, 256, 0, stream>>>(h2s_hi[T & 1], h2s_lo[T & 1], Wl, bl,
                                           input, nullptr,
                                           out + (T - 1), T + 1);
}

// Round 6
// 5220.796 us; speedup vs baseline: 6.5982x; 6.5982x over previous
//
#include <hip/hip_runtime.h>
#include <math.h>

#define NINP 64
#define NH 512
#define G4 2048   // 4*NH
#define T 64
#define BATCH 2048
#define LDIN 4097 // T*NINP+1
#define XCOLS 4096

typedef __bf16 bf16x8 __attribute__((ext_vector_type(8)));
typedef float f32x4 __attribute__((ext_vector_type(4)));
typedef unsigned short ushort8 __attribute__((ext_vector_type(8)));

__device__ __forceinline__ float sigmf(float x) { return 1.0f / (1.0f + expf(-x)); }

__device__ __forceinline__ unsigned int bfhi_bits(float f) {
    unsigned int u = __float_as_uint(f);
    return (u + 0x7fffu + ((u >> 16) & 1u)) >> 16;
}
__device__ __forceinline__ float bf_to_f(unsigned int bits) {
    return __uint_as_float(bits << 16);
}

// ---------------------------------------------------------------------------
// Fused gates-GEMM (split-bf16 MFMA) + LSTM cell epilogue.
// 256 threads / 4 waves (2m x 2n), block tile 128(b) x 64(n'), wave 64x32.
// BK=32. LDS: 64B rows, XOR swizzle slot^=(row>>1)&3 -> conflict-free
// (verified: SQ_LDS_BANK_CONFLICT = 0 in R5). 49152B LDS -> 3 blocks/CU.
// Double-buffered K-pipeline, register prefetch, 1 barrier per K-step.
// Gate columns PERMUTED: n' = j*4 + g.
// XCD-pinned mapping (bid&7) keeps each XCD's W slice L2-resident.
// Optional prologue: out-projection of previous step's h (+ pia scaling).
// ---------------------------------------------------------------------------
#define OFF_AHI 0
#define OFF_ALO 4096
#define OFF_WHI 8192
#define OFF_WLO 10240
#define BUFSZ   12288   // ushorts per buffer (24576 B)

__global__ __launch_bounds__(256) void lstm_step_k(
    const ushort* __restrict__ A0hi, const ushort* __restrict__ A0lo, int lda0,
    const ushort* __restrict__ W0hi, const ushort* __restrict__ W0lo, int K0,
    const ushort* __restrict__ A1hi, const ushort* __restrict__ A1lo, int lda1,
    const ushort* __restrict__ W1hi, const ushort* __restrict__ W1lo, int K1,
    const ushort* __restrict__ A2hi, const ushort* __restrict__ A2lo, int lda2,
    const ushort* __restrict__ W2hi, const ushort* __restrict__ W2lo, int K2,
    const float* __restrict__ biasperm,
    const float* __restrict__ pv, const float* __restrict__ pcperm,
    float* __restrict__ c,
    ushort* __restrict__ hhi, ushort* __restrict__ hlo,
    const ushort* __restrict__ ophi, const ushort* __restrict__ oplo,
    const float* __restrict__ Wl, const float* __restrict__ blv,
    const float* __restrict__ scaleBase,
    float* __restrict__ piadst,
    float* __restrict__ odst, int ostride)
{
    __shared__ __align__(16) ushort smem[2 * BUFSZ];   // 49152 B
    float* Gs = (float*)smem;                          // [128][68] aliased (34816 B)

    const int tid = threadIdx.x;
    const int lane = tid & 63;
    const int wid = tid >> 6;
    const int bid = blockIdx.x;

    // XCD-pinned tile mapping
    const int xcd = bid & 7;
    const int idx8 = bid >> 3;
    const int nblk = xcd * 4 + (idx8 & 3);
    const int mblk = idx8 >> 2;
    const int m0 = mblk * 128;
    const int n0 = nblk * 64;

    // ---- prologue: out-projection of previous h ----
    if (ophi != nullptr) {
        int row = bid * 4 + wid;
        ushort8 hh8 = *(const ushort8*)&ophi[(size_t)row * NH + lane * 8];
        ushort8 hl8 = *(const ushort8*)&oplo[(size_t)row * NH + lane * 8];
        const float4* wv = (const float4*)(Wl + lane * 8);
        float4 w0 = wv[0], w1 = wv[1];
        float wreg[8] = {w0.x, w0.y, w0.z, w0.w, w1.x, w1.y, w1.z, w1.w};
        float s = 0.f;
        #pragma unroll
        for (int e = 0; e < 8; ++e) {
            float h = bf_to_f(hh8[e]) + bf_to_f(hl8[e]);
            s = fmaf(h, wreg[e], s);
        }
        #pragma unroll
        for (int off = 32; off > 0; off >>= 1) s += __shfl_down(s, off);
        if (lane == 0) {
            float proj = s + blv[0];
            if (odst) odst[(size_t)row * ostride] = proj;
            if (piadst) piadst[row] = fabsf(proj) * scaleBase[(size_t)row * LDIN + (LDIN - 1)];
        }
    }

    // wave geometry: 2m x 2n, wave tile 64x32
    const int wm = wid >> 1;
    const int wn = wid & 1;
    const int fr = lane & 15;
    const int fg = lane >> 4;
    const int rdsw = (fr >> 1) & 3;     // read swizzle (base rows are mult of 16)

    // staging geometry: A 128 rows x 4 slots; W 64 rows x 4 slots (hi+lo)
    const int srow = tid >> 2;          // 0..63
    const int aslot = tid & 3;
    const int swa0 = (aslot ^ ((srow >> 1) & 3)) << 3;            // row srow
    const int swa1 = (aslot ^ (((srow + 64) >> 1) & 3)) << 3;     // row srow+64

    const int nt0 = K0 >> 5;
    const int nt1 = K1 >> 5;
    const int nt2 = K2 >> 5;
    const int NT = nt0 + nt1 + nt2;

    ushort8 ra0, rl0, ra1, rl1, rwh, rwl;

    auto issue = [&](int t) {
        const ushort *Ahi, *Alo, *Whi, *Wlo;
        int lda_, K_, kt;
        if (t < nt0)            { Ahi = A0hi; Alo = A0lo; lda_ = lda0; K_ = K0; kt = t * 32;
                                  Whi = W0hi; Wlo = W0lo; }
        else if (t < nt0 + nt1) { Ahi = A1hi; Alo = A1lo; lda_ = lda1; K_ = K1; kt = (t - nt0) * 32;
                                  Whi = W1hi; Wlo = W1lo; }
        else                    { Ahi = A2hi; Alo = A2lo; lda_ = lda2; K_ = K2; kt = (t - nt0 - nt1) * 32;
                                  Whi = W2hi; Wlo = W2lo; }
        const size_t acol = (size_t)kt + aslot * 8;
        ra0 = *(const ushort8*)&Ahi[(size_t)(m0 + srow) * lda_ + acol];
        rl0 = *(const ushort8*)&Alo[(size_t)(m0 + srow) * lda_ + acol];
        ra1 = *(const ushort8*)&Ahi[(size_t)(m0 + srow + 64) * lda_ + acol];
        rl1 = *(const ushort8*)&Alo[(size_t)(m0 + srow + 64) * lda_ + acol];
        rwh = *(const ushort8*)&Whi[(size_t)(n0 + srow) * K_ + acol];
        rwl = *(const ushort8*)&Wlo[(size_t)(n0 + srow) * K_ + acol];
    };

    auto dswr = [&](int buf) {
        ushort* bp = smem + buf * BUFSZ;
        *(ushort8*)&bp[OFF_AHI + srow * 32 + swa0] = ra0;
        *(ushort8*)&bp[OFF_ALO + srow * 32 + swa0] = rl0;
        *(ushort8*)&bp[OFF_AHI + (srow + 64) * 32 + swa1] = ra1;
        *(ushort8*)&bp[OFF_ALO + (srow + 64) * 32 + swa1] = rl1;
        *(ushort8*)&bp[OFF_WHI + srow * 32 + swa0] = rwh;
        *(ushort8*)&bp[OFF_WLO + srow * 32 + swa0] = rwl;
    };

    f32x4 acc[4][2] = {};
    int cur = 0;

    issue(0);
    dswr(0);

    for (int t = 0; t < NT; ++t) {
        if (t + 1 < NT) issue(t + 1);
        __syncthreads();

        const ushort* bp = smem + cur * BUFSZ;
        bf16x8 ah[4], al[4], wh[2], wl[2];
        #pragma unroll
        for (int im = 0; im < 4; ++im) {
            int off = (wm * 64 + im * 16 + fr) * 32 + ((fg ^ rdsw) << 3);
            ah[im] = *(const bf16x8*)&bp[OFF_AHI + off];
            al[im] = *(const bf16x8*)&bp[OFF_ALO + off];
        }
        #pragma unroll
        for (int in = 0; in < 2; ++in) {
            int off = (wn * 32 + in * 16 + fr) * 32 + ((fg ^ rdsw) << 3);
            wh[in] = *(const bf16x8*)&bp[OFF_WHI + off];
            wl[in] = *(const bf16x8*)&bp[OFF_WLO + off];
        }
        #pragma unroll
        for (int im = 0; im < 4; ++im)
            #pragma unroll
            for (int in = 0; in < 2; ++in)
                acc[im][in] = __builtin_amdgcn_mfma_f32_16x16x32_bf16(ah[im], wh[in], acc[im][in], 0, 0, 0);
        #pragma unroll
        for (int im = 0; im < 4; ++im)
            #pragma unroll
            for (int in = 0; in < 2; ++in)
                acc[im][in] = __builtin_amdgcn_mfma_f32_16x16x32_bf16(ah[im], wl[in], acc[im][in], 0, 0, 0);
        #pragma unroll
        for (int im = 0; im < 4; ++im)
            #pragma unroll
            for (int in = 0; in < 2; ++in)
                acc[im][in] = __builtin_amdgcn_mfma_f32_16x16x32_bf16(al[im], wh[in], acc[im][in], 0, 0, 0);

        if (t + 1 < NT) dswr(cur ^ 1);
        cur ^= 1;
    }

    // ---- epilogue stage 1: bias + pia, fragments -> LDS f32 [128][68] ----
    __syncthreads();
    #pragma unroll
    for (int im = 0; im < 4; ++im) {
        int rowl = wm * 64 + im * 16 + fg * 4;
        #pragma unroll
        for (int in = 0; in < 2; ++in) {
            int npl = wn * 32 + in * 16 + fr;
            int np = n0 + npl;
            float bias = biasperm[np];
            float pcv = (pcperm != nullptr) ? pcperm[np] : 0.0f;
            #pragma unroll
            for (int r = 0; r < 4; ++r) {
                float g = acc[im][in][r] + bias;
                if (pv != nullptr) g += pv[m0 + rowl + r] * pcv;
                Gs[(rowl + r) * 68 + npl] = g;
            }
        }
    }
    __syncthreads();

    // ---- epilogue stage 2: per-cell update, coalesced I/O ----
    {
        int brow = tid >> 1;            // 0..127
        int j8 = (tid & 1) * 8;
        size_t idx = (size_t)(m0 + brow) * NH + (n0 >> 2) + j8;
        float4 cold0 = *(const float4*)&c[idx];
        float4 cold1 = *(const float4*)&c[idx + 4];
        float co[8] = {cold0.x, cold0.y, cold0.z, cold0.w,
                       cold1.x, cold1.y, cold1.z, cold1.w};
        float cn[8], hn[8];
        #pragma unroll
        for (int jj = 0; jj < 8; ++jj) {
            float4 gv = *(const float4*)&Gs[brow * 68 + (j8 + jj) * 4];
            float cnv = sigmf(gv.y) * co[jj] + sigmf(gv.x) * tanhf(gv.z);
            cn[jj] = cnv;
            hn[jj] = sigmf(gv.w) * tanhf(cnv);
        }
        float4 cs0 = {cn[0], cn[1], cn[2], cn[3]};
        float4 cs1 = {cn[4], cn[5], cn[6], cn[7]};
        *(float4*)&c[idx] = cs0;
        *(float4*)&c[idx + 4] = cs1;
        ushort8 hh, hl;
        #pragma unroll
        for (int jj = 0; jj < 8; ++jj) {
            unsigned int hb = bfhi_bits(hn[jj]);
            hh[jj] = (unsigned short)hb;
            hl[jj] = (unsigned short)bfhi_bits(hn[jj] - bf_to_f(hb));
        }
        *(ushort8*)&hhi[idx] = hh;
        *(ushort8*)&hlo[idx] = hl;
    }
}

// Standalone out-projection from hi/lo split h (tail), with optional pia.
__global__ __launch_bounds__(256) void out_proj_hl(const ushort* __restrict__ hhi,
                                                   const ushort* __restrict__ hlo,
                                                   const float* __restrict__ Wl,
                                                   const float* __restrict__ blv,
                                                   const float* __restrict__ scaleBase,
                                                   float* __restrict__ piadst,
                                                   float* __restrict__ odst, int ostride)
{
    int wave = threadIdx.x >> 6;
    int lane = threadIdx.x & 63;
    int row = blockIdx.x * 4 + wave;
    ushort8 hh8 = *(const ushort8*)&hhi[(size_t)row * NH + lane * 8];
    ushort8 hl8 = *(const ushort8*)&hlo[(size_t)row * NH + lane * 8];
    const float4* wv = (const float4*)(Wl + lane * 8);
    float4 w0 = wv[0], w1 = wv[1];
    float wreg[8] = {w0.x, w0.y, w0.z, w0.w, w1.x, w1.y, w1.z, w1.w};
    float s = 0.f;
    #pragma unroll
    for (int e = 0; e < 8; ++e) {
        float h = bf_to_f(hh8[e]) + bf_to_f(hl8[e]);
        s = fmaf(h, wreg[e], s);
    }
    #pragma unroll
    for (int off = 32; off > 0; off >>= 1) s += __shfl_down(s, off);
    if (lane == 0) {
        float proj = s + blv[0];
        if (odst) odst[(size_t)row * ostride] = proj;
        if (piadst) piadst[row] = fabsf(proj) * scaleBase[(size_t)row * LDIN + (LDIN - 1)];
    }
}

// Split W[4NH][ldw] (cols 0..K-1) into permuted bf16 hi/lo, n' = j*4+g.
__global__ __launch_bounds__(256) void split_perm_w_k(const float* __restrict__ W,
                                                      ushort* __restrict__ whi,
                                                      ushort* __restrict__ wlo,
                                                      int ldw, int kshift)
{
    int idx = blockIdx.x * 256 + threadIdx.x;
    int K = 1 << kshift;
    int np = idx >> kshift;
    int k = idx & (K - 1);
    int orig = ((np & 3) << 9) | (np >> 2);
    float v = W[(size_t)orig * ldw + k];
    unsigned int hb = bfhi_bits(v);
    whi[idx] = (unsigned short)hb;
    wlo[idx] = (unsigned short)bfhi_bits(v - bf_to_f(hb));
}

// Split input x (cols 0..4095) into bf16 hi/lo, layout [b][4096].
__global__ __launch_bounds__(256) void split_x_k(const float* __restrict__ input,
                                                 ushort* __restrict__ xhi,
                                                 ushort* __restrict__ xlo)
{
    int idx = blockIdx.x * 256 + threadIdx.x;   // over BATCH*XCOLS
    int b = idx >> 12;
    int col = idx & (XCOLS - 1);
    float v = input[(size_t)b * LDIN + col];
    unsigned int hb = bfhi_bits(v);
    xhi[idx] = (unsigned short)hb;
    xlo[idx] = (unsigned short)bfhi_bits(v - bf_to_f(hb));
}

__global__ __launch_bounds__(256) void bias_prep_k(const float* __restrict__ bih,
                                                   const float* __restrict__ bhh,
                                                   float* __restrict__ bperm)
{
    int np = blockIdx.x * 256 + threadIdx.x;
    int orig = ((np & 3) << 9) | (np >> 2);
    bperm[np] = bih[orig] + bhh[orig];
}

__global__ __launch_bounds__(256) void pc_prep_k(const float* __restrict__ Wih1,
                                                 float* __restrict__ pc)
{
    int np = blockIdx.x * 256 + threadIdx.x;
    int orig = ((np & 3) << 9) | (np >> 2);
    pc[np] = Wih1[(size_t)orig * (NINP + 1) + NINP];
}

extern "C" void kernel_launch(void* const* d_in, const int* in_sizes, int n_in,
                              void* d_out, int out_size, void* d_ws, size_t ws_size,
                              hipStream_t stream)
{
    const float* input = (const float*)d_in[0];
    const float* Wih_p = (const float*)d_in[1];
    const float* Whh_p = (const float*)d_in[2];
    const float* bih_p = (const float*)d_in[3];
    const float* bhh_p = (const float*)d_in[4];
    const float* Wih1  = (const float*)d_in[5];
    const float* Whh1  = (const float*)d_in[6];
    const float* bih1  = (const float*)d_in[7];
    const float* bhh1  = (const float*)d_in[8];
    const float* Wih2  = (const float*)d_in[9];
    const float* Whh2  = (const float*)d_in[10];
    const float* bih2  = (const float*)d_in[11];
    const float* bhh2  = (const float*)d_in[12];
    const float* Wl    = (const float*)d_in[13];
    const float* bl    = (const float*)d_in[14];
    float* out = (float*)d_out;

    const size_t HC = (size_t)BATCH * NH;       // 1M elems
    char* p = (char*)d_ws;
    auto alloc = [&](size_t bytes) { char* r = p; p += (bytes + 255) & ~(size_t)255; return r; };

    // --- zeroed region first ---
    float* c_p = (float*)alloc(HC * 4);
    float* c1  = (float*)alloc(HC * 4);
    float* c2  = (float*)alloc(HC * 4);
    ushort* hps_hi[2]; ushort* hps_lo[2];
    ushort* h1s_hi[2]; ushort* h1s_lo[2];
    ushort* h2s_hi[2]; ushort* h2s_lo[2];
    for (int i = 0; i < 2; ++i) { hps_hi[i] = (ushort*)alloc(HC * 2); hps_lo[i] = (ushort*)alloc(HC * 2); }
    for (int i = 0; i < 2; ++i) { h1s_hi[i] = (ushort*)alloc(HC * 2); h1s_lo[i] = (ushort*)alloc(HC * 2); }
    for (int i = 0; i < 2; ++i) { h2s_hi[i] = (ushort*)alloc(HC * 2); h2s_lo[i] = (ushort*)alloc(HC * 2); }
    size_t zbytes = (size_t)(p - (char*)d_ws);

    // --- non-zeroed ---
    float* pias   = (float*)alloc((size_t)T * BATCH * 4);
    ushort* WhhP_hi = (ushort*)alloc((size_t)G4 * NH * 2);
    ushort* WhhP_lo = (ushort*)alloc((size_t)G4 * NH * 2);
    ushort* WihP_hi = (ushort*)alloc((size_t)G4 * NINP * 2);
    ushort* WihP_lo = (ushort*)alloc((size_t)G4 * NINP * 2);
    ushort* Whh1_hi = (ushort*)alloc((size_t)G4 * NH * 2);
    ushort* Whh1_lo = (ushort*)alloc((size_t)G4 * NH * 2);
    ushort* Wih1x_hi = (ushort*)alloc((size_t)G4 * NINP * 2);
    ushort* Wih1x_lo = (ushort*)alloc((size_t)G4 * NINP * 2);
    ushort* Wih2_hi = (ushort*)alloc((size_t)G4 * NH * 2);
    ushort* Wih2_lo = (ushort*)alloc((size_t)G4 * NH * 2);
    ushort* Whh2_hi = (ushort*)alloc((size_t)G4 * NH * 2);
    ushort* Whh2_lo = (ushort*)alloc((size_t)G4 * NH * 2);
    ushort* xhi = (ushort*)alloc((size_t)BATCH * XCOLS * 2);
    ushort* xlo = (ushort*)alloc((size_t)BATCH * XCOLS * 2);
    float* biasP = (float*)alloc(G4 * 4);
    float* bias1 = (float*)alloc(G4 * 4);
    float* bias2 = (float*)alloc(G4 * 4);
    float* pc1   = (float*)alloc(G4 * 4);

    hipMemsetAsync(d_ws, 0, zbytes, stream);

    // prep
    split_perm_w_k<<<(G4 * NH) / 256, 256, 0, stream>>>(Whh_p, WhhP_hi, WhhP_lo, NH, 9);
    split_perm_w_k<<<(G4 * NINP) / 256, 256, 0, stream>>>(Wih_p, WihP_hi, WihP_lo, NINP, 6);
    split_perm_w_k<<<(G4 * NH) / 256, 256, 0, stream>>>(Whh1, Whh1_hi, Whh1_lo, NH, 9);
    split_perm_w_k<<<(G4 * NINP) / 256, 256, 0, stream>>>(Wih1, Wih1x_hi, Wih1x_lo, NINP + 1, 6);
    split_perm_w_k<<<(G4 * NH) / 256, 256, 0, stream>>>(Wih2, Wih2_hi, Wih2_lo, NH, 9);
    split_perm_w_k<<<(G4 * NH) / 256, 256, 0, stream>>>(Whh2, Whh2_hi, Whh2_lo, NH, 9);
    split_x_k<<<(BATCH * XCOLS) / 256, 256, 0, stream>>>(input, xhi, xlo);
    bias_prep_k<<<G4 / 256, 256, 0, stream>>>(bih_p, bhh_p, biasP);
    bias_prep_k<<<G4 / 256, 256, 0, stream>>>(bih1, bhh1, bias1);
    bias_prep_k<<<G4 / 256, 256, 0, stream>>>(bih2, bhh2, bias2);
    pc_prep_k<<<G4 / 256, 256, 0, stream>>>(Wih1, pc1);

    dim3 sgrid(512);
    dim3 sblk(256);
    dim3 ogrid(BATCH / 4);

    // Phase 1
    for (int t = 0; t < T; ++t) {
        int rb = t & 1, wb = (t + 1) & 1;
        lstm_step_k<<<sgrid, sblk, 0, stream>>>(
            xhi + (size_t)t * NINP, xlo + (size_t)t * NINP, XCOLS,
            WihP_hi, WihP_lo, NINP,
            hps_hi[rb], hps_lo[rb], NH, WhhP_hi, WhhP_lo, NH,
            nullptr, nullptr, 0, nullptr, nullptr, 0,
            biasP, nullptr, nullptr,
            c_p, hps_hi[wb], hps_lo[wb],
            (t > 0) ? hps_hi[rb] : nullptr, hps_lo[rb], Wl, bl,
            input, (t > 0) ? pias + (size_t)(t - 1) * BATCH : nullptr,
            nullptr, 0);
    }
    out_proj_hl<<<ogrid, 256, 0, stream>>>(hps_hi[T & 1], hps_lo[T & 1], Wl, bl,
                                           input, pias + (size_t)(T - 1) * BATCH,
                                           out + T, T + 1);

    // Phase 2
    for (int t = 0; t < T; ++t) {
        int rb = t & 1, wb = (t + 1) & 1;
        lstm_step_k<<<sgrid, sblk, 0, stream>>>(
            xhi + (size_t)t * NINP, xlo + (size_t)t * NINP, XCOLS,
            Wih1x_hi, Wih1x_lo, NINP,
            h1s_hi[rb], h1s_lo[rb], NH, Whh1_hi, Whh1_lo, NH,
            nullptr, nullptr, 0, nullptr, nullptr, 0,
            bias1, pias + (size_t)t * BATCH, pc1,
            c1, h1s_hi[wb], h1s_lo[wb],
            (t > 0) ? h2s_hi[rb] : nullptr, h2s_lo[rb], Wl, bl,
            input, nullptr,
            (t > 0) ? out + (t - 1) : nullptr, T + 1);
        lstm_step_k<<<sgrid, sblk, 0, stream>>>(
            h1s_hi[wb], h1s_lo[wb], NH, Wih2_hi, Wih2_lo, NH,
            h2s_hi[rb], h2s_lo[rb], NH, Whh2_hi, Whh2_lo, NH,
            nullptr, nullptr, 0, nullptr, nullptr, 0,
            bias2, nullptr, nullptr,
            c2, h2s_hi[wb], h2s_lo[wb],
            nullptr, nullptr, nullptr, nullptr,
            nullptr, nullptr, nullptr, 0);
    }
    out_proj_hl<<<ogrid, 256, 0, stream>>>(h2s_hi[T & 1], h2s_lo[T & 1], Wl, bl,
                                           input, nullptr,
                                           out + (T - 1), T + 1);
}